// Round 4
// baseline (344.994 us; speedup 1.0000x reference)
//
#include <hip/hip_runtime.h>

// CircuitModel: sequential Oja/Hebbian plasticity scan.
//   y_t = sigmoid(w_t.x_t); w_{t+1} = b_t*w_t + a_t*x_t,
//   a_t = lr*th0*y_t, b_t = 1 + lr*th1*y_t^2; out[t,p] = y_t at observed rows.
//
// R1-R17: see journal. R15 best = 191.6us scan (1 wave/row, D=8 blocks).
// R18: re-baseline 192.0us confirmed.
// R19 REGRESSED (265us scan): 4-way N_IN split + per-block LDS barrier.
//   Lesson: wall time = 256 x per-ROW critical path (rows all parallel);
//   the barrier+LDS+s_load-contaminated lgkmcnt added ~700cy/block, more
//   than the ~1000cy of issue slots it removed. VALUBusy 46% = half idle.
// R20: DECOUPLE the reduce from the w-chain. Boundary dots for block t+1
//   computed with OLD w during block t (u[d] = w_t . x_{t+1,d}), then
//   corrected via the same linearization as in-block:
//     q(t+1)[d] = B*u[d] + sum_i c_i * Gx[i][d],
//   Gx = cross-block 8x8 Gram tile (precomputed, fp16, per-lane column).
//   Chain/block = SL(~256cy) + prefix-c + 9-fma correction ~ 350cy; the
//   DPP+LDS+barrier reduce overlaps the SL. SL runs BEFORE the barrier
//   (absorbs skew); band s_loads issue post-barrier (clean lgkmcnt(0)).
//   P layout: 240B/block = 28 f32 band + 64 fp16 Gx = 60KB total (fits
//   the known-safe 64KB workspace).
// R21: container failed twice (infra, same as R18's failure mode — R18's
//   identical-resubmit then passed). Audited for hang paths: barrier
//   uniform, vmcnt drains reachable, LDS dbuf race-free. Resubmitted
//   unchanged.

constexpr int N_IN    = 512;
constexpr int T       = 2048;
constexpr int N_OBS   = 256;
constexpr int D       = 8;            // linearization block size
constexpr int NBLK    = T / D;        // 256
constexpr int PSTRIDE = 240;          // bytes per block: 112 band + 128 fp16 Gx
constexpr float LOG2E = 1.44269504088896f;

typedef float f4 __attribute__((ext_vector_type(4)));
typedef float f2 __attribute__((ext_vector_type(2)));
typedef _Float16 h8 __attribute__((ext_vector_type(8)));

// Packed band layout for block b (t0=8b): entry k = x_{t0+i}.x_{t0+i+j},
// k = BOFF[i] + (j-1), i=0..6, j=1..7-i (28 entries).
__device__ constexpr int BOFF[8] = {0, 7, 13, 18, 22, 25, 27, 28};

// DPP add-reduce step via builtin (old=0 additive identity; compiler handles
// the VALU->DPP hazard slots — R14 lesson).
#define DPP_ADD(v, ctrl, rmask)                                                \
    v += __int_as_float(__builtin_amdgcn_update_dpp(                           \
        0, __float_as_int(v), (ctrl), (rmask), 0xf, false))

__device__ __forceinline__ float wave64_sum_bcast(float v) {
    DPP_ADD(v, 0x111, 0xf); // row_shr:1
    DPP_ADD(v, 0x112, 0xf); // row_shr:2
    DPP_ADD(v, 0x114, 0xf); // row_shr:4
    DPP_ADD(v, 0x118, 0xf); // row_shr:8
    DPP_ADD(v, 0x142, 0xa); // row_bcast:15
    DPP_ADD(v, 0x143, 0xc); // row_bcast:31 -> lane63 = total
    return __int_as_float(__builtin_amdgcn_readlane(__float_as_int(v), 63));
}

// Serial-fma lane-partial dot over 8 elements (gram kernel).
__device__ __forceinline__ float dot8s(const f4& w0, const f4& w1,
                                       const f4& x0, const f4& x1) {
    float p = w0.x * x0.x;
    p = fmaf(w0.y, x0.y, p);
    p = fmaf(w0.z, x0.z, p);
    p = fmaf(w0.w, x0.w, p);
    p = fmaf(w1.x, x1.x, p);
    p = fmaf(w1.y, x1.y, p);
    p = fmaf(w1.z, x1.z, p);
    p = fmaf(w1.w, x1.w, p);
    return p;
}

// ---- explicit-VMEM primitives ---------------------------------------------
#define GLOADX2(dst, addr, offstr)                                             \
    asm volatile("global_load_dwordx2 %0, %1, off offset:" offstr              \
                 : "=v"(dst) : "v"(addr))
#define GLOADX4(dst, addr, offstr)                                             \
    asm volatile("global_load_dwordx4 %0, %1, off offset:" offstr              \
                 : "=v"(dst) : "v"(addr))

// Stage one block: 8 x-row slices (f2 per lane) + 1 Gx column load (f4 = 8
// fp16). Exactly 9 vmem issues, program-ordered.
__device__ __forceinline__ void stage9(f2 (&xb)[8], f4& gx,
                                       const char* xa, const char* ga) {
    const char* a0 = xa;
    const char* a1 = xa + 4096;
    const char* a2 = xa + 8192;
    const char* a3 = xa + 12288;
    GLOADX2(xb[0], a0, "0");  GLOADX2(xb[1], a0, "2048");
    GLOADX2(xb[2], a1, "0");  GLOADX2(xb[3], a1, "2048");
    GLOADX2(xb[4], a2, "0");  GLOADX2(xb[5], a2, "2048");
    GLOADX2(xb[6], a3, "0");  GLOADX2(xb[7], a3, "2048");
    GLOADX4(gx, ga, "0");
}

// Wait: drain all but the newest N outstanding vmem ops, tying the x buffer
// and Gx column whose values we are about to consume.
#define WAITN(nstr, XB, GX)                                                    \
    asm volatile("s_waitcnt vmcnt(" nstr ")"                                   \
        : "+v"(XB[0]), "+v"(XB[1]), "+v"(XB[2]), "+v"(XB[3]),                  \
          "+v"(XB[4]), "+v"(XB[5]), "+v"(XB[6]), "+v"(XB[7]), "+v"(GX))

__device__ __forceinline__ void load_band(float (&bs)[28], const float* pb) {
    #pragma unroll
    for (int k = 0; k < 28; ++k) bs[k] = pb[k];   // wave-uniform -> s_load
}

// ---- Kernel 1: packed Gram band + cross tile, one wave per block -----------
__global__ __launch_bounds__(64, 1) void gram_kernel(const float* __restrict__ X,
                                                     char* __restrict__ P) {
    const int b    = blockIdx.x;          // 0..NBLK-1
    const int lane = threadIdx.x;         // 0..63
    const int t0   = b * D;
    const int bn   = (b + 1 < NBLK) ? (b + 1) : b;   // clamp (tile zeroed)
    const float xv = (b + 1 < NBLK) ? 1.0f : 0.0f;
    const f4* Xv = (const f4*)(X + (long)t0 * N_IN);
    const f4* Xn = (const f4*)(X + (long)bn * D * N_IN);
    f4 r[8][2], rn[8][2];
    #pragma unroll
    for (int i = 0; i < 8; ++i) {
        r[i][0]  = Xv[i * (N_IN / 4) + lane * 2 + 0];
        r[i][1]  = Xv[i * (N_IN / 4) + lane * 2 + 1];
        rn[i][0] = Xn[i * (N_IN / 4) + lane * 2 + 0];
        rn[i][1] = Xn[i * (N_IN / 4) + lane * 2 + 1];
    }
    // In-block band (28 entries).
    float s[28];
    #pragma unroll
    for (int i = 0; i < 7; ++i) {
        #pragma unroll
        for (int j = 1; j <= 7 - i; ++j) {
            s[BOFF[i] + j - 1] =
                wave64_sum_bcast(dot8s(r[i][0], r[i][1], r[i + j][0], r[i + j][1]));
        }
    }
    // Cross tile Gx[i][d] = x_{t0+i} . x_{t0+8+d}, column-major (d outer) so
    // the scan's lane d reads 8 contiguous fp16.
    float g[64];
    #pragma unroll
    for (int d = 0; d < 8; ++d) {
        #pragma unroll
        for (int i = 0; i < 8; ++i) {
            g[d * 8 + i] = xv *
                wave64_sum_bcast(dot8s(r[i][0], r[i][1], rn[d][0], rn[d][1]));
        }
    }
    if (lane == 0) {
        float* pf = (float*)(P + (size_t)b * PSTRIDE);
        #pragma unroll
        for (int k = 0; k < 28; ++k) pf[k] = s[k];
        _Float16* ph = (_Float16*)(P + (size_t)b * PSTRIDE + 112);
        #pragma unroll
        for (int k = 0; k < 64; ++k) ph[k] = (_Float16)g[k];
    }
}

// ---- Kernel 2: the scan ----------------------------------------------------
// One WG (4 waves) per observed row; wave wid owns N_IN slice
// [wid*128, wid*128+128), 2 floats per lane. Weights in log2e space.
__global__ __launch_bounds__(256, 1) void oja_scan_kernel(
    const float* __restrict__ X,     // [T, N_IN]
    const float* __restrict__ Winit, // [N_OUT, N_IN]
    const float* __restrict__ theta, // [2]
    const int*   __restrict__ obs,   // [N_OBS]
    const char*  __restrict__ P,     // [NBLK] x PSTRIDE bytes (d_ws)
    float*       __restrict__ out)   // [T, N_OBS]
{
    __shared__ __align__(16) float smem[64];  // 2 bufs x 8 dots x 4 waves

    const int tid  = threadIdx.x;
    const int wid  = tid >> 6;            // 0..3 (1 wave per SIMD)
    const int lane = tid & 63;
    const int col  = blockIdx.x;          // observed-row index 0..255

    const int row = obs[col];
    const float lr   = 1.0f / (float)N_IN;
    const float th0s = theta[0] * lr * LOG2E;  // log2e-space a coefficient
    const float th1  = theta[1] * lr;

    const f2* Wv = (const f2*)(Winit + (long)row * N_IN + wid * 128);
    f2 w = Wv[lane];
    w.x *= LOG2E; w.y *= LOG2E;

    const char* xbase  = (const char*)X + (size_t)(wid * 128 + lane * 2) * 4;
    const char* gxbase = P + 112 + (size_t)(lane & 7) * 16;  // fp16 column d

    f2 x0[8], x1[8], x2[8], x3[8];
    f4 g0, g1, g2, g3;
    float bsA[28], bsB[28];
    float q[D];                           // q~ for the current block (uniform)

    // ---- Prologue: stage blocks 0,1; boundary reduce gives q(0) directly.
    stage9(x0, g0, xbase, gxbase);
    stage9(x1, g1, xbase + 16384, gxbase + PSTRIDE);
    load_band(bsA, (const float*)P);
    WAITN("0", x0, g0);
    {
        float qp[D];
        #pragma unroll
        for (int d = 0; d < D; ++d) {
            float p = x0[d].x * w.x;
            p = fmaf(x0[d].y, w.y, p);
            qp[d] = wave64_sum_bcast(p);
        }
        float packv = qp[0];
        #pragma unroll
        for (int d = 1; d < D; ++d) packv = (lane == d) ? qp[d] : packv;
        if (lane < D) smem[32 + lane * 4 + wid] = packv;   // prologue: buf 1
        asm volatile("s_waitcnt lgkmcnt(0)" ::: "memory");
        __builtin_amdgcn_s_barrier();
        asm volatile("" ::: "memory");
        const f4 qq = *(const f4*)&smem[32 + (lane & 7) * 4];
        const float u = (qq.x + qq.y) + (qq.z + qq.w);
        #pragma unroll
        for (int d = 0; d < D; ++d)
            q[d] = __int_as_float(
                __builtin_amdgcn_readlane(__float_as_int(u), d));
    }

// One block: stage t+2, dot NEXT block's x with current w (overlapped
// reduce), run the scalar loop + w-update + store BEFORE the barrier, then
// read the reduce, apply the Gx correction, readlane q for the next block.
#define STEP(CUR, NXT, STG, GXC, GXS, BSC, BSN, LB, tval)                      \
    do {                                                                       \
        const int t_  = (tval);                                                \
        const int ts_ = (t_ + 2 < NBLK) ? (t_ + 2) : (NBLK - 1);               \
        const int tn_ = (t_ + 1 < NBLK) ? (t_ + 1) : (NBLK - 1);               \
        stage9(STG, GXS, xbase + (size_t)ts_ * 16384,                          \
               gxbase + (size_t)ts_ * PSTRIDE);                                \
        WAITN("10", NXT, GXC);                                                 \
        /* boundary dots for block t+1 with OLD w (pre-update) */              \
        float qp_[D];                                                          \
        _Pragma("unroll")                                                      \
        for (int d = 0; d < D; ++d) {                                          \
            float p_ = NXT[d].x * w.x;                                         \
            p_ = fmaf(NXT[d].y, w.y, p_);                                      \
            qp_[d] = wave64_sum_bcast(p_);                                     \
        }                                                                      \
        float packv_ = qp_[0];                                                 \
        _Pragma("unroll")                                                      \
        for (int d = 1; d < D; ++d) packv_ = (lane == d) ? qp_[d] : packv_;    \
        if (lane < D) smem[(LB) * 32 + lane * 4 + wid] = packv_;               \
        /* scalar loop for block t (uniform, redundant across waves) */        \
        float av_[D], bv_[D];                                                  \
        float ys_ = 0.0f;                                                      \
        float z_  = q[0];                                                      \
        _Pragma("unroll")                                                      \
        for (int i = 0; i < D; ++i) {                                          \
            const float y_ =                                                   \
                __builtin_amdgcn_rcpf(1.0f + __builtin_amdgcn_exp2f(-z_));     \
            if (lane == i) ys_ = y_;                                           \
            const float a_ = th0s * y_;                                        \
            const float b_ = fmaf(th1 * y_, y_, 1.0f);                         \
            av_[i] = a_; bv_[i] = b_;                                          \
            _Pragma("unroll")                                                  \
            for (int d = i + 1; d < D; ++d)                                    \
                q[d] = fmaf(b_, q[d], a_ * BSC[BOFF[i] + (d - i) - 1]);        \
            if (i < D - 1) z_ = q[i + 1];                                      \
        }                                                                      \
        float c_[D];                                                           \
        float sfx_ = 1.0f;                                                     \
        _Pragma("unroll")                                                      \
        for (int i = D - 1; i >= 0; --i) { c_[i] = av_[i] * sfx_;              \
                                           sfx_ *= bv_[i]; }                   \
        const float B_ = sfx_;                                                 \
        /* w-update on this wave's slice, using block t's x (CUR) */           \
        f2 acc_;                                                               \
        acc_.x = c_[0] * CUR[0].x;                                             \
        acc_.y = c_[0] * CUR[0].y;                                             \
        _Pragma("unroll")                                                      \
        for (int i = 1; i < D; ++i) {                                          \
            acc_.x = fmaf(c_[i], CUR[i].x, acc_.x);                            \
            acc_.y = fmaf(c_[i], CUR[i].y, acc_.y);                            \
        }                                                                      \
        w.x = fmaf(B_, w.x, acc_.x);                                           \
        w.y = fmaf(B_, w.y, acc_.y);                                           \
        /* store y_0..y_7 (lanes 0..7, exec-masked; all 4 waves redundant) */  \
        {                                                                      \
            float* oaddr_ = out + (size_t)(t_ * D + lane) * N_OBS + col;       \
            asm volatile("s_mov_b64 vcc, exec\n\t"                             \
                         "s_mov_b64 exec, 0xff\n\t"                            \
                         "global_store_dword %0, %1, off\n\t"                  \
                         "s_mov_b64 exec, vcc"                                 \
                         :: "v"(oaddr_), "v"(ys_) : "vcc");                    \
        }                                                                      \
        /* now complete the cross-wave reduce (off the w-chain until here) */  \
        asm volatile("s_waitcnt lgkmcnt(0)" ::: "memory");                     \
        __builtin_amdgcn_s_barrier();                                          \
        asm volatile("" ::: "memory");                                        \
        const f4 qq_ = *(const f4*)&smem[(LB) * 32 + (lane & 7) * 4];          \
        const float u_ = (qq_.x + qq_.y) + (qq_.z + qq_.w);                    \
        h8 gh_;                                                                \
        __builtin_memcpy(&gh_, &GXC, 16);                                      \
        float qn_ = B_ * u_;                                                   \
        _Pragma("unroll")                                                      \
        for (int i = 0; i < D; ++i)                                            \
            qn_ = fmaf(c_[i], (float)gh_[i], qn_);                             \
        _Pragma("unroll")                                                      \
        for (int d = 0; d < D; ++d)                                            \
            q[d] = __int_as_float(                                             \
                __builtin_amdgcn_readlane(__float_as_int(qn_), d));            \
        /* band for block t+1 (s_loads far from the next lgkmcnt(0)) */        \
        load_band(BSN, (const float*)(P + (size_t)tn_ * PSTRIDE));             \
    } while (0)

    for (int blk = 0; blk < NBLK; blk += 4) {
        STEP(x0, x1, x2, g0, g2, bsA, bsB, 0, blk + 0);
        STEP(x1, x2, x3, g1, g3, bsB, bsA, 1, blk + 1);
        STEP(x2, x3, x0, g2, g0, bsA, bsB, 0, blk + 2);
        STEP(x3, x0, x1, g3, g1, bsB, bsA, 1, blk + 3);
    }
#undef STEP
}

extern "C" void kernel_launch(void* const* d_in, const int* in_sizes, int n_in,
                              void* d_out, int out_size, void* d_ws, size_t ws_size,
                              hipStream_t stream) {
    const float* X     = (const float*)d_in[0];
    const float* Winit = (const float*)d_in[1];
    const float* theta = (const float*)d_in[2];
    const int*   obs   = (const int*)d_in[3];
    float*       out   = (float*)d_out;
    char*        P     = (char*)d_ws;   // NBLK * 240 B = 60 KB

    // Gram band + cross tiles: one wave per block.
    gram_kernel<<<NBLK, 64, 0, stream>>>(X, P);

    // Scan: 256 WGs x 4 waves = 1024 waves.
    oja_scan_kernel<<<256, 256, 0, stream>>>(X, Winit, theta, obs, P, out);
}

// Round 8
// 328.044 us; speedup vs baseline: 1.0517x; 1.0517x over previous
//
#include <hip/hip_runtime.h>

// CircuitModel: sequential Oja/Hebbian plasticity scan.
//   y_t = sigmoid(w_t.x_t); w_{t+1} = b_t*w_t + a_t*x_t,
//   a_t = lr*th0*y_t, b_t = 1 + lr*th1*y_t^2; out[t,p] = y_t at observed rows.
//
// R15 best = 191.6us scan / 248 total (1 wave/row, D=8 blocks).
// R19/R20 REGRESSED (265/307us): cross-wave split; barrier cost > slot gain.
// R22 CRASHED: dot-free recurrence, but 512KB d_ws (only 64KB safe).
// R23 FAILED absmax 0.99: junk tail-restages created same-physreg WAW:
//   junk load (dead def) + next phase's load into the same C variable were
//   simultaneously in flight; regalloc shares the physreg (old def dead),
//   VMEM returns are out-of-order -> stale junk data can land LAST,
//   silently replacing next-superblock x rows. LESSON: never reissue a
//   load into a buffer until a wait has RETIRED that buffer's previous
//   load; vmcnt retire order != register writeback order.
// R24: same dot-free recurrence, WAW-free staging. No junk loads;
//   per-phase wait schedule 16,16,16,16,16,16,8,0 (tail drains). G-quarters
//   Q0/Q1 hoisted to v-init start (oldest in queue, retired by the x-wait
//   drains, zero extra waits); Q2/Q3 issued only after their buffer is
//   consumed+retired. Every architectural buffer has <=1 in-flight load.
// R25: container failed twice (infra; 3rd occurrence — Rounds 0,3 same, both
//   resubmits then ran). Re-audited vmcnt ledger + packed-triangle dead-lane
//   dataflow: clean. Resubmitted unchanged.

constexpr int N_IN  = 512;
constexpr int T     = 2048;
constexpr int N_OBS = 256;
constexpr int SBS   = 32;          // superblock steps
constexpr int NSB   = T / SBS;     // 64
constexpr int TILEB = 1024;        // packed fp16 tile stride (content 994B)
constexpr float LOG2E = 1.44269504088896f;

typedef float f4 __attribute__((ext_vector_type(4)));

__device__ __forceinline__ float rdlanef(float v, int l) {
    return __int_as_float(__builtin_amdgcn_readlane(__float_as_int(v), l));
}

__device__ __forceinline__ float h2f(unsigned int u) {
    unsigned short s = (unsigned short)u;
    _Float16 h;
    __builtin_memcpy(&h, &s, 2);
    return (float)h;                      // v_cvt_f32_f16
}

// Partial dot over this lane's 8 elements.
__device__ __forceinline__ float dot8s(const f4& w0, const f4& w1,
                                       const f4& x0, const f4& x1) {
    float p = w0.x * x0.x;
    p = fmaf(w0.y, x0.y, p);
    p = fmaf(w0.z, x0.z, p);
    p = fmaf(w0.w, x0.w, p);
    p = fmaf(w1.x, x1.x, p);
    p = fmaf(w1.y, x1.y, p);
    p = fmaf(w1.z, x1.z, p);
    p = fmaf(w1.w, x1.w, p);
    return p;
}

// ---- explicit-VMEM primitives ---------------------------------------------
#define GLOADX4(dst, addr, offstr)                                             \
    asm volatile("global_load_dwordx4 %0, %1, off offset:" offstr              \
                 : "=v"(dst) : "v"(addr))
#define GLOADU(dst, addr, offstr)                                              \
    asm volatile("global_load_ushort %0, %1, off offset:" offstr               \
                 : "=v"(dst) : "v"(addr))

// Stage 4 x-rows' 8-float lane slices: 8 dwordx4 issues, program-ordered.
// base = X + sb_row0*2048B + lane*32B; group g covers rows 4g..4g+3.
#define STAGE4(buf, base, g) do {                                              \
    const char* a_ = (base) + (size_t)(g) * 8192;                              \
    GLOADX4(buf[0], a_,        "0");  GLOADX4(buf[1], a_,        "16");        \
    GLOADX4(buf[2], a_ + 2048, "0");  GLOADX4(buf[3], a_ + 2048, "16");        \
    GLOADX4(buf[4], a_ + 4096, "0");  GLOADX4(buf[5], a_ + 4096, "16");        \
    GLOADX4(buf[6], a_ + 6144, "0");  GLOADX4(buf[7], a_ + 6144, "16");        \
} while (0)

#define TIE8(ins, b)                                                           \
    asm volatile(ins : "+v"(b[0]), "+v"(b[1]), "+v"(b[2]), "+v"(b[3]),         \
                       "+v"(b[4]), "+v"(b[5]), "+v"(b[6]), "+v"(b[7]))
#define WAIT16(b) TIE8("s_waitcnt vmcnt(16)", b)  // drain to 16 outstanding
#define WAIT8(b)  TIE8("s_waitcnt vmcnt(8)", b)
#define WAIT0(b)  TIE8("s_waitcnt vmcnt(0)", b)

// G-row loads: packed upper-tri, row t starts at byte SH(t)=60t-t(t-1);
// lane reads SH(t) + 2*min(lane,31) -> always within the 1024B tile.
#define STAGEG_Q0(buf, ga) do {                                                \
    GLOADU(buf[0], ga, "0");   GLOADU(buf[1], ga, "60");                       \
    GLOADU(buf[2], ga, "118"); GLOADU(buf[3], ga, "174");                      \
    GLOADU(buf[4], ga, "228"); GLOADU(buf[5], ga, "280");                      \
    GLOADU(buf[6], ga, "330"); GLOADU(buf[7], ga, "378"); } while (0)
#define STAGEG_Q1(buf, ga) do {                                                \
    GLOADU(buf[0], ga, "424"); GLOADU(buf[1], ga, "468");                      \
    GLOADU(buf[2], ga, "510"); GLOADU(buf[3], ga, "550");                      \
    GLOADU(buf[4], ga, "588"); GLOADU(buf[5], ga, "624");                      \
    GLOADU(buf[6], ga, "658"); GLOADU(buf[7], ga, "690"); } while (0)
#define STAGEG_Q2(buf, ga) do {                                                \
    GLOADU(buf[0], ga, "720"); GLOADU(buf[1], ga, "748");                      \
    GLOADU(buf[2], ga, "774"); GLOADU(buf[3], ga, "798");                      \
    GLOADU(buf[4], ga, "820"); GLOADU(buf[5], ga, "840");                      \
    GLOADU(buf[6], ga, "858"); GLOADU(buf[7], ga, "874"); } while (0)
#define STAGEG_Q3(buf, ga) do {                                                \
    GLOADU(buf[0], ga, "888"); GLOADU(buf[1], ga, "900");                      \
    GLOADU(buf[2], ga, "910"); GLOADU(buf[3], ga, "918");                      \
    GLOADU(buf[4], ga, "924"); GLOADU(buf[5], ga, "928");                      \
    GLOADU(buf[6], ga, "930"); GLOADU(buf[7], ga, "930"); } while (0)

// DPP row_shl with 1.0-fill (old=0x3f800000, bound_ctrl=false).
#define DPPM(srcf, ctrl)                                                       \
    __int_as_float(__builtin_amdgcn_update_dpp(                                \
        0x3f800000, __float_as_int(srcf), (ctrl), 0xf, 0xf, false))

// ---- Kernel 1: packed upper-tri Gram tiles (fp16) --------------------------
// block = (sb, iq); half h computes row i = iq*2+h vs all j = lane&31.
__global__ __launch_bounds__(64) void gram_kernel(const float* __restrict__ X,
                                                  char* __restrict__ G) {
    const int bid  = blockIdx.x;
    const int sb   = bid >> 4;            // 0..63
    const int iq   = bid & 15;            // 0..15
    const int lane = threadIdx.x;
    const int h    = lane >> 5;
    const int j    = lane & 31;
    const int i    = iq * 2 + h;          // 0..31

    const f4* xi = (const f4*)(X + ((size_t)sb * SBS + i) * N_IN);
    const f4* xj = (const f4*)(X + ((size_t)sb * SBS + j) * N_IN);

    f4 acc = {0.f, 0.f, 0.f, 0.f};
    #pragma unroll 8
    for (int c = 0; c < N_IN / 4; ++c) {
        const f4 u  = xi[c];
        const f4 vv = xj[c];
        acc.x = fmaf(u.x, vv.x, acc.x);
        acc.y = fmaf(u.y, vv.y, acc.y);
        acc.z = fmaf(u.z, vv.z, acc.z);
        acc.w = fmaf(u.w, vv.w, acc.w);
    }
    const float gv = (acc.x + acc.y) + (acc.z + acc.w);

    char* tile = G + (size_t)sb * TILEB;
    const int sh = 60 * i - i * (i - 1);  // row-start byte
    if (j > i)
        *(_Float16*)(tile + sh + 2 * j) = (_Float16)gv;
    if (bid == 0 && lane == 0)
        *(_Float16*)G = (_Float16)0.0f;   // guard (dead read t=0,lane=0)
}

// ---- 8 scalar steps (t = tb..tb+7) -----------------------------------------
__device__ __forceinline__ void steps8(const unsigned int (&g)[8], int tb,
                                       int lane, float th0s, float th1,
                                       float& v, float& ysv, float& avv,
                                       float& bvv) {
    #pragma unroll
    for (int j = 0; j < 8; ++j) {
        const int t = tb + j;
        const float z = rdlanef(v, t);    // v[t] before its own update
        const float y =
            __builtin_amdgcn_rcpf(1.0f + __builtin_amdgcn_exp2f(-z));
        const float a = th0s * y;         // log2e-space coefficient
        const float b = fmaf(th1 * y, y, 1.0f);
        if (lane == t) { ysv = y; avv = a; bvv = b; }
        v = fmaf(b, v, a * h2f(g[j]));    // v <- w~_{t+1} . x_lane
    }
}

// ---- Kernel 2: the scan (1 wave per observed row, no barriers) -------------
__global__ __launch_bounds__(64, 1) void oja_scan_kernel(
    const float* __restrict__ X,     // [T, N_IN]
    const float* __restrict__ Winit, // [N_OUT, N_IN]
    const float* __restrict__ theta, // [2]
    const int*   __restrict__ obs,   // [N_OBS]
    const char*  __restrict__ Gm,    // 64 packed fp16 tiles (d_ws, 64KB)
    float*       __restrict__ out)   // [T, N_OBS]
{
    __shared__ float lds[SBS * 68];  // 32x68 transpose scratch (8704B)

    const int lane = threadIdx.x;    // 0..63
    const int col  = blockIdx.x;     // observed-row index

    const int row = obs[col];
    const float lr   = 1.0f / (float)N_IN;
    const float th0s = theta[0] * lr * LOG2E;
    const float th1  = theta[1] * lr;

    // Lane owns w elements [8*lane, 8*lane+8), held in log2e space.
    const f4* Wv = (const f4*)(Winit + (size_t)row * N_IN + lane * 8);
    f4 w0b = Wv[0];
    f4 w1b = Wv[1];
    w0b *= LOG2E;
    w1b *= LOG2E;

    const int laneC = (lane < 32) ? lane : 31;          // G/lds clamp
    const char* xlane = (const char*)X + (size_t)lane * 32;
    const char* gl    = Gm + (size_t)laneC * 2;

    f4 ub[3][8];                     // rotating x-stage buffers
    unsigned int gA[8], gB[8];       // G double-buffer (raw fp16 in u32)
    float v = 0.f, ysv = 0.f, avv = 0.f, bvv = 1.0f;

    // 4 partial-dot rows into the LDS transpose scratch.
    auto putrows = [&](const f4 (&b)[8], int r0) {
        #pragma unroll
        for (int k = 0; k < 4; ++k)
            lds[(r0 + k) * 68 + lane] =
                dot8s(w0b, w1b, b[2 * k], b[2 * k + 1]);
    };

    #pragma unroll 1
    for (int sb = 0; sb < NSB; ++sb) {
        const char* xsb = xlane + (size_t)sb * SBS * 2048;   // 64KB per sb
        const char* ga  = gl + (size_t)sb * TILEB;

        // ---- v-init: v[lane] = w~ . x_{sb*32+lane} (lanes 0..31) ----------
        // G quarters Q0/Q1 first (oldest in queue -> retired by x drains).
        STAGEG_Q0(gA, ga);
        STAGEG_Q1(gB, ga);
        STAGE4(ub[0], xsb, 0);
        STAGE4(ub[1], xsb, 1);
        STAGE4(ub[2], xsb, 2);
        WAIT16(ub[0]); putrows(ub[0], 0);  STAGE4(ub[0], xsb, 3);
        WAIT16(ub[1]); putrows(ub[1], 4);  STAGE4(ub[1], xsb, 4);
        WAIT16(ub[2]); putrows(ub[2], 8);  STAGE4(ub[2], xsb, 5);
        WAIT16(ub[0]); putrows(ub[0], 12); STAGE4(ub[0], xsb, 6);
        WAIT16(ub[1]); putrows(ub[1], 16); STAGE4(ub[1], xsb, 7);
        WAIT16(ub[2]); putrows(ub[2], 20);
        WAIT8 (ub[0]); putrows(ub[0], 24);
        WAIT0 (ub[1]); putrows(ub[1], 28);
        asm volatile("s_waitcnt lgkmcnt(0)" ::: "memory");
        {
            const f4* lr4 = (const f4*)&lds[laneC * 68];  // 272B rows, aligned
            f4 s0 = lr4[0] + lr4[1];
            f4 s1 = lr4[2] + lr4[3];
            f4 s2 = lr4[4] + lr4[5];
            f4 s3 = lr4[6] + lr4[7];
            f4 s4 = lr4[8] + lr4[9];
            f4 s5 = lr4[10] + lr4[11];
            f4 s6 = lr4[12] + lr4[13];
            f4 s7 = lr4[14] + lr4[15];
            s0 += s1; s2 += s3; s4 += s5; s6 += s7;
            s0 += s2; s4 += s6;
            s0 += s4;
            v = (s0.x + s0.y) + (s0.z + s0.w);
        }

        // ---- scalar phase: 32 steps (gA/gB already retired; Q2/Q3 issue
        // only after their buffer's data is consumed AND retired) ------------
        steps8(gA, 0,  lane, th0s, th1, v, ysv, avv, bvv);
        STAGEG_Q2(gA, ga);
        steps8(gB, 8,  lane, th0s, th1, v, ysv, avv, bvv);
        STAGEG_Q3(gB, ga);
        WAIT8(gA);  steps8(gA, 16, lane, th0s, th1, v, ysv, avv, bvv);
        WAIT0(gB);  steps8(gB, 24, lane, th0s, th1, v, ysv, avv, bvv);

        // ---- store y (lanes 0..31, exec-masked) ----------------------------
        {
            float* oaddr = out + ((size_t)(sb * SBS) + lane) * N_OBS + col;
            asm volatile("s_mov_b64 vcc, exec\n\t"
                         "s_mov_b32 exec_lo, -1\n\t"
                         "s_mov_b32 exec_hi, 0\n\t"
                         "global_store_dword %0, %1, off\n\t"
                         "s_mov_b64 exec, vcc"
                         :: "v"(oaddr), "v"(ysv) : "vcc");
        }

        // ---- batched w-update (skip at last sb) ----------------------------
        if (sb < NSB - 1) {
            // Exclusive suffix product within 16-lane rows (DPP shl scan),
            // then cross-row factors. Lanes 32..63: bvv=1, avv=0 always.
            float E = DPPM(bvv, 0x101);
            E *= DPPM(E, 0x101);
            E *= DPPM(E, 0x102);
            E *= DPPM(E, 0x104);
            E *= DPPM(E, 0x108);
            const float RP = bvv * E;        // inclusive suffix within row
            const float R0 = rdlanef(RP, 0);
            const float R1 = rdlanef(RP, 16);
            const float R2 = rdlanef(RP, 32);   // = 1
            const float R3 = rdlanef(RP, 48);   // = 1
            const float F2v = R3;
            const float F1v = F2v * R2;
            const float F0v = F1v * R1;
            const float Btot = F0v * R0;
            const int rid = lane >> 4;
            const float F = (rid == 3) ? 1.0f
                          : (rid == 2) ? F2v
                          : (rid == 1) ? F1v : F0v;
            const float cvv = avv * (E * F); // c_t = a_t * prod_{j>t} b_j

            w0b *= Btot;
            w1b *= Btot;

            auto wacc = [&](const f4 (&b)[8], int t0) {
                #pragma unroll
                for (int k = 0; k < 4; ++k) {
                    const float cs = rdlanef(cvv, t0 + k);
                    const f4 xa = b[2 * k];
                    const f4 xb = b[2 * k + 1];
                    w0b.x = fmaf(cs, xa.x, w0b.x);
                    w0b.y = fmaf(cs, xa.y, w0b.y);
                    w0b.z = fmaf(cs, xa.z, w0b.z);
                    w0b.w = fmaf(cs, xa.w, w0b.w);
                    w1b.x = fmaf(cs, xb.x, w1b.x);
                    w1b.y = fmaf(cs, xb.y, w1b.y);
                    w1b.z = fmaf(cs, xb.z, w1b.z);
                    w1b.w = fmaf(cs, xb.w, w1b.w);
                }
            };

            STAGE4(ub[0], xsb, 0);
            STAGE4(ub[1], xsb, 1);
            STAGE4(ub[2], xsb, 2);
            WAIT16(ub[0]); wacc(ub[0], 0);  STAGE4(ub[0], xsb, 3);
            WAIT16(ub[1]); wacc(ub[1], 4);  STAGE4(ub[1], xsb, 4);
            WAIT16(ub[2]); wacc(ub[2], 8);  STAGE4(ub[2], xsb, 5);
            WAIT16(ub[0]); wacc(ub[0], 12); STAGE4(ub[0], xsb, 6);
            WAIT16(ub[1]); wacc(ub[1], 16); STAGE4(ub[1], xsb, 7);
            WAIT16(ub[2]); wacc(ub[2], 20);
            WAIT8 (ub[0]); wacc(ub[0], 24);
            WAIT0 (ub[1]); wacc(ub[1], 28);
        }
    }

    asm volatile("s_waitcnt vmcnt(0)");   // drain stores before endpgm
}

extern "C" void kernel_launch(void* const* d_in, const int* in_sizes, int n_in,
                              void* d_out, int out_size, void* d_ws, size_t ws_size,
                              hipStream_t stream) {
    const float* X     = (const float*)d_in[0];
    const float* Winit = (const float*)d_in[1];
    const float* theta = (const float*)d_in[2];
    const int*   obs   = (const int*)d_in[3];
    float*       out   = (float*)d_out;
    char*        G     = (char*)d_ws;   // 64 tiles x 1024B = 65536B (safe)

    // Packed Gram tiles: 64 sb x 16 row-pairs.
    gram_kernel<<<NSB * 16, 64, 0, stream>>>(X, G);

    // Scan: 256 WGs x 1 wave, one per observed row.
    oja_scan_kernel<<<N_OBS, 64, 0, stream>>>(X, Winit, theta, obs, G, out);
}